// Round 2
// baseline (5140.841 us; speedup 1.0000x reference)
//
#include <hip/hip_runtime.h>
#include <hip/hip_bf16.h>
#include <math.h>

// SpaFormer forward, fp32 baseline (correctness-first).
// B=16 N=512 L=4 H=8 DK=DV=64 DM=512 DI=2048 M=64
//
// ws layout (floats), compact (f_mid aliases dead q/k/v/t during FFN):
//   f_x   @ 0         (8192x512)
//   f_q   @ 4194304   (8192x512)   \
//   f_k   @ 8388608   (8192x512)    | f_mid @ 4194304 (8192x2048) aliases these
//   f_v   @ 12582912  (8192x512)    | (q/k/v/t dead when FFN runs)
//   f_t   @ 16777216  (8192x512)   /
//   f_t2  @ 20971520  (8192x512)
// total 25165824 floats = 100.7 MB

// ---------------- feature-encoder first linear (K=3) ----------------
__global__ __launch_bounds__(256) void fe1_kernel(
        const float* __restrict__ feat, const float* __restrict__ w1,
        const float* __restrict__ b1, float* __restrict__ out) {
    int idx = blockIdx.x * 256 + threadIdx.x;   // 8192*512 threads
    int r = idx >> 9, j = idx & 511;
    float f0 = feat[r * 3 + 0], f1 = feat[r * 3 + 1], f2 = feat[r * 3 + 2];
    out[(size_t)r * 512 + j] =
        fmaf(f0, w1[j], fmaf(f1, w1[512 + j], fmaf(f2, w1[1024 + j], b1[j])));
}

// ---------------- generic fp32 GEMM: C = A(MxK) @ W(Kxcols) + bias (+res) ----------------
// 128x128 tile, BK=32, 256 threads, 8x8 per thread. rows/cols multiples of 128, K mult of 32.
// EPI: 0 none, 1 relu, 2 gelu(erf)
template<int EPI>
__global__ __launch_bounds__(256, 2) void gemm_kernel(
        const float* __restrict__ A, const float* __restrict__ W,
        const float* __restrict__ bias, const float* __restrict__ res,
        float* __restrict__ C, int K, int cols) {
    __shared__ float At[32][132];   // K-major transposed A tile
    __shared__ float Wt[32][132];
    const int tid = threadIdx.x;
    const int c0 = blockIdx.x * 128;
    const int r0 = blockIdx.y * 128;
    const int tx = tid & 15, ty = tid >> 4;

    float acc[8][8];
#pragma unroll
    for (int i = 0; i < 8; i++)
#pragma unroll
        for (int j = 0; j < 8; j++) acc[i][j] = 0.f;

    for (int k0 = 0; k0 < K; k0 += 32) {
        // stage A tile (transpose to K-major)
#pragma unroll
        for (int t = 0; t < 4; t++) {
            int idx = tid + t * 256;          // 1024 float4 slots
            int row = idx >> 3, c4 = idx & 7;
            float4 av = *(const float4*)&A[(size_t)(r0 + row) * K + k0 + c4 * 4];
            At[c4 * 4 + 0][row] = av.x;
            At[c4 * 4 + 1][row] = av.y;
            At[c4 * 4 + 2][row] = av.z;
            At[c4 * 4 + 3][row] = av.w;
        }
        // stage W tile (already K-major)
#pragma unroll
        for (int t = 0; t < 4; t++) {
            int idx = tid + t * 256;          // 1024 float4 slots
            int kk = idx >> 5, c4 = idx & 31;
            *(float4*)&Wt[kk][c4 * 4] =
                *(const float4*)&W[(size_t)(k0 + kk) * cols + c0 + c4 * 4];
        }
        __syncthreads();
#pragma unroll
        for (int kk = 0; kk < 32; kk++) {
            float a[8], b[8];
            *(float4*)&a[0] = *(float4*)&At[kk][ty * 8];
            *(float4*)&a[4] = *(float4*)&At[kk][ty * 8 + 4];
            *(float4*)&b[0] = *(float4*)&Wt[kk][tx * 8];
            *(float4*)&b[4] = *(float4*)&Wt[kk][tx * 8 + 4];
#pragma unroll
            for (int i = 0; i < 8; i++)
#pragma unroll
                for (int j = 0; j < 8; j++)
                    acc[i][j] = fmaf(a[i], b[j], acc[i][j]);
        }
        __syncthreads();
    }

    float bvv[8];
    *(float4*)&bvv[0] = *(const float4*)&bias[c0 + tx * 8];
    *(float4*)&bvv[4] = *(const float4*)&bias[c0 + tx * 8 + 4];
#pragma unroll
    for (int i = 0; i < 8; i++) {
        size_t r = (size_t)r0 + ty * 8 + i;
        float o[8];
#pragma unroll
        for (int j = 0; j < 8; j++) o[j] = acc[i][j] + bvv[j];
        if (res) {
            float rv[8];
            *(float4*)&rv[0] = *(const float4*)&res[r * cols + c0 + tx * 8];
            *(float4*)&rv[4] = *(const float4*)&res[r * cols + c0 + tx * 8 + 4];
#pragma unroll
            for (int j = 0; j < 8; j++) o[j] += rv[j];
        }
#pragma unroll
        for (int j = 0; j < 8; j++) {
            if (EPI == 1) o[j] = fmaxf(o[j], 0.f);
            if (EPI == 2) o[j] = 0.5f * o[j] * (1.f + erff(o[j] * 0.7071067811865475f));
        }
        *(float4*)&C[r * cols + c0 + tx * 8] = *(float4*)&o[0];
        *(float4*)&C[r * cols + c0 + tx * 8 + 4] = *(float4*)&o[4];
    }
}

// ---------------- LayerNorm over last dim (512), one wave per row ----------------
__global__ __launch_bounds__(256) void ln_kernel(
        const float* __restrict__ in, float* __restrict__ out,
        const float* __restrict__ g, const float* __restrict__ b) {
    const int lane = threadIdx.x & 63;
    const size_t row = (size_t)blockIdx.x * 4 + (threadIdx.x >> 6);
    const float* x = in + row * 512;
    float4 a0 = *(const float4*)&x[lane * 4];
    float4 a1 = *(const float4*)&x[256 + lane * 4];
    float s = a0.x + a0.y + a0.z + a0.w + a1.x + a1.y + a1.z + a1.w;
#pragma unroll
    for (int off = 32; off >= 1; off >>= 1) s += __shfl_xor(s, off);
    float mean = s * (1.f / 512.f);
    float d, vs = 0.f;
    d = a0.x - mean; vs += d * d;
    d = a0.y - mean; vs += d * d;
    d = a0.z - mean; vs += d * d;
    d = a0.w - mean; vs += d * d;
    d = a1.x - mean; vs += d * d;
    d = a1.y - mean; vs += d * d;
    d = a1.z - mean; vs += d * d;
    d = a1.w - mean; vs += d * d;
#pragma unroll
    for (int off = 32; off >= 1; off >>= 1) vs += __shfl_xor(vs, off);
    float inv = rsqrtf(vs * (1.f / 512.f) + 1e-6f);
    float4 g0 = *(const float4*)&g[lane * 4];
    float4 g1 = *(const float4*)&g[256 + lane * 4];
    float4 b0 = *(const float4*)&b[lane * 4];
    float4 b1v = *(const float4*)&b[256 + lane * 4];
    float* y = out + row * 512;
    float4 o0, o1;
    o0.x = (a0.x - mean) * inv * g0.x + b0.x;
    o0.y = (a0.y - mean) * inv * g0.y + b0.y;
    o0.z = (a0.z - mean) * inv * g0.z + b0.z;
    o0.w = (a0.w - mean) * inv * g0.w + b0.w;
    o1.x = (a1.x - mean) * inv * g1.x + b1v.x;
    o1.y = (a1.y - mean) * inv * g1.y + b1v.y;
    o1.z = (a1.z - mean) * inv * g1.z + b1v.z;
    o1.w = (a1.w - mean) * inv * g1.w + b1v.w;
    *(float4*)&y[lane * 4] = o0;
    *(float4*)&y[256 + lane * 4] = o1;
}

// ---------------- fused attention: scores + rel-pos + softmax + PV ----------------
// grid (N/32, B), 256 threads. Loops 8 heads; 32 Q-rows per block; full 512-wide
// score rows live in LDS (no flash rescale needed since N=512 fits).
__global__ __launch_bounds__(256, 1) void attn_kernel(
        const float* __restrict__ q, const float* __restrict__ k,
        const float* __restrict__ v, const float* __restrict__ rpos,
        const float* __restrict__ wp, const float* __restrict__ bp,
        float* __restrict__ out) {
    __shared__ float qs[32][68];     // q tile (one head)
    __shared__ float sc[32][520];    // scores -> probs
    __shared__ float kv[128][68];    // k/v chunk
    __shared__ float qw3[32][4];     // qw (p=0..2) + q.bp
    const int tid = threadIdx.x;
    const int b = blockIdx.y;
    const int n0 = blockIdx.x * 32;
    const float scale = 0.125f;      // 1/sqrt(64)

    for (int h = 0; h < 8; h++) {
        // ---- load Q tile for this head ----
#pragma unroll
        for (int t = 0; t < 2; t++) {
            int idx = tid + t * 256;           // 512 float4 slots
            int r = idx >> 4, c4 = idx & 15;
            *(float4*)&qs[r][c4 * 4] =
                *(const float4*)&q[((size_t)(b * 512 + n0 + r)) * 512 + h * 64 + c4 * 4];
        }
        __syncthreads();
        // ---- qw[r][p] = q . wp[p,h,:]; qw3[r][3] = q . bp[h,:] ----
        if (tid < 128) {
            int r = tid >> 2, j = tid & 3;
            const float* wvec = (j < 3) ? (wp + ((size_t)j * 8 + h) * 64) : (bp + (size_t)h * 64);
            float s = 0.f;
#pragma unroll
            for (int d = 0; d < 64; d++) s = fmaf(qs[r][d], wvec[d], s);
            qw3[r][j] = s;
        }
        __syncthreads();

        // ---- scores: 4 chunks of 128 keys ----
        const int rb = (tid >> 3) & 7;                  // 8 row-blocks of 4
        const int mb = (tid & 7) + (tid >> 6) * 8;      // 32 m-blocks of 4, wave-local
        for (int mc = 0; mc < 4; mc++) {
#pragma unroll
            for (int t = 0; t < 8; t++) {
                int idx = tid + t * 256;       // 2048 float4 slots
                int mm = idx >> 4, c4 = idx & 15;
                *(float4*)&kv[mm][c4 * 4] =
                    *(const float4*)&k[((size_t)(b * 512 + mc * 128 + mm)) * 512 + h * 64 + c4 * 4];
            }
            __syncthreads();
            float acc[4][4];
#pragma unroll
            for (int i = 0; i < 4; i++)
#pragma unroll
                for (int j = 0; j < 4; j++) acc[i][j] = 0.f;
#pragma unroll
            for (int dd = 0; dd < 16; dd++) {
                float4 qv[4], kf[4];
#pragma unroll
                for (int i = 0; i < 4; i++) qv[i] = *(float4*)&qs[rb * 4 + i][dd * 4];
#pragma unroll
                for (int j = 0; j < 4; j++) kf[j] = *(float4*)&kv[mb * 4 + j][dd * 4];
#pragma unroll
                for (int i = 0; i < 4; i++)
#pragma unroll
                    for (int j = 0; j < 4; j++) {
                        acc[i][j] = fmaf(qv[i].x, kf[j].x, acc[i][j]);
                        acc[i][j] = fmaf(qv[i].y, kf[j].y, acc[i][j]);
                        acc[i][j] = fmaf(qv[i].z, kf[j].z, acc[i][j]);
                        acc[i][j] = fmaf(qv[i].w, kf[j].w, acc[i][j]);
                    }
            }
            // rel-pos term + store raw scores
#pragma unroll
            for (int i = 0; i < 4; i++) {
                int r = rb * 4 + i;
                const float* rp =
                    rpos + (((size_t)(b * 512) + n0 + r) * 512 + mc * 128 + mb * 4) * 3;
                float w0 = qw3[r][0], w1 = qw3[r][1], w2 = qw3[r][2], w3 = qw3[r][3];
#pragma unroll
                for (int j = 0; j < 4; j++) {
                    float rel = fmaf(w0, rp[j * 3 + 0],
                                fmaf(w1, rp[j * 3 + 1],
                                fmaf(w2, rp[j * 3 + 2], w3)));
                    sc[r][mc * 128 + mb * 4 + j] = acc[i][j] + rel;
                }
            }
            __syncthreads();
        }

        // ---- softmax over m (512), 8 lanes per row ----
        {
            int r = tid >> 3, jl = tid & 7;
            float mx = -1e30f;
#pragma unroll 8
            for (int t = 0; t < 64; t++) mx = fmaxf(mx, sc[r][jl + 8 * t]);
#pragma unroll
            for (int off = 1; off < 8; off <<= 1) mx = fmaxf(mx, __shfl_xor(mx, off));
            float sum = 0.f;
#pragma unroll 8
            for (int t = 0; t < 64; t++) {
                int m = jl + 8 * t;
                float e = __expf((sc[r][m] - mx) * scale);
                sc[r][m] = e;
                sum += e;
            }
#pragma unroll
            for (int off = 1; off < 8; off <<= 1) sum += __shfl_xor(sum, off);
            float invs = 1.0f / sum;
#pragma unroll 8
            for (int t = 0; t < 64; t++) sc[r][jl + 8 * t] *= invs;
        }
        __syncthreads();

        // ---- PV: out[r][d] = sum_m p[r][m] v[m][d] ----
        float po[8];
#pragma unroll
        for (int j = 0; j < 8; j++) po[j] = 0.f;
        const int pr = tid >> 3, dg = tid & 7;
        for (int mc = 0; mc < 4; mc++) {
#pragma unroll
            for (int t = 0; t < 8; t++) {
                int idx = tid + t * 256;
                int mm = idx >> 4, c4 = idx & 15;
                *(float4*)&kv[mm][c4 * 4] =
                    *(const float4*)&v[((size_t)(b * 512 + mc * 128 + mm)) * 512 + h * 64 + c4 * 4];
            }
            __syncthreads();
#pragma unroll 8
            for (int mm = 0; mm < 128; mm++) {
                float p = sc[pr][mc * 128 + mm];
                float4 va = *(float4*)&kv[mm][dg * 8];
                float4 vb = *(float4*)&kv[mm][dg * 8 + 4];
                po[0] = fmaf(p, va.x, po[0]);
                po[1] = fmaf(p, va.y, po[1]);
                po[2] = fmaf(p, va.z, po[2]);
                po[3] = fmaf(p, va.w, po[3]);
                po[4] = fmaf(p, vb.x, po[4]);
                po[5] = fmaf(p, vb.y, po[5]);
                po[6] = fmaf(p, vb.z, po[6]);
                po[7] = fmaf(p, vb.w, po[7]);
            }
            __syncthreads();
        }
        float4 o0 = make_float4(po[0], po[1], po[2], po[3]);
        float4 o1 = make_float4(po[4], po[5], po[6], po[7]);
        float* op = &out[((size_t)(b * 512 + n0 + pr)) * 512 + h * 64 + dg * 8];
        *(float4*)&op[0] = o0;
        *(float4*)&op[4] = o1;
        __syncthreads();   // before next head reuses qs/sc/kv
    }
}

// ---------------- gather masked positions ----------------
__global__ __launch_bounds__(256) void gather_kernel(
        const float* __restrict__ x, const int* __restrict__ mp,
        float* __restrict__ h1) {
    int idx = blockIdx.x * 256 + threadIdx.x;   // 1024 rows * 128 float4
    int row = idx >> 7, c4 = idx & 127;
    int b = row >> 6;
    int src = mp[row];
    *(float4*)&h1[(size_t)row * 512 + c4 * 4] =
        *(const float4*)&x[((size_t)(b * 512 + src)) * 512 + c4 * 4];
}

// ---------------- final decoder dot (512 -> 1), one wave per row ----------------
__global__ __launch_bounds__(256) void dec2_kernel(
        const float* __restrict__ dmid, const float* __restrict__ w2,
        const float* __restrict__ b2, float* __restrict__ out) {
    const int lane = threadIdx.x & 63;
    const int row = blockIdx.x * 4 + (threadIdx.x >> 6);
    float s = 0.f;
#pragma unroll
    for (int t = 0; t < 8; t++) {
        int c = lane + t * 64;
        s = fmaf(dmid[(size_t)row * 512 + c], w2[c], s);
    }
#pragma unroll
    for (int off = 32; off >= 1; off >>= 1) s += __shfl_xor(s, off);
    if (lane == 0) out[row] = s + b2[0];
}

extern "C" void kernel_launch(void* const* d_in, const int* in_sizes, int n_in,
                              void* d_out, int out_size, void* d_ws, size_t ws_size,
                              hipStream_t stream) {
    const float* feat   = (const float*)d_in[0];
    const float* rpos   = (const float*)d_in[1];
    const int*   mpos   = (const int*)d_in[2];
    const float* fe_w1  = (const float*)d_in[3];
    const float* fe_b1  = (const float*)d_in[4];
    const float* fe_w2  = (const float*)d_in[5];
    const float* fe_b2  = (const float*)d_in[6];
    const float* wq     = (const float*)d_in[7];
    const float* bq     = (const float*)d_in[8];
    const float* wk     = (const float*)d_in[9];
    const float* bk     = (const float*)d_in[10];
    const float* wv     = (const float*)d_in[11];
    const float* bv     = (const float*)d_in[12];
    const float* wp     = (const float*)d_in[13];
    const float* bp     = (const float*)d_in[14];
    const float* wo     = (const float*)d_in[15];
    const float* bo     = (const float*)d_in[16];
    const float* ln1_g  = (const float*)d_in[17];
    const float* ln1_b  = (const float*)d_in[18];
    const float* ffn_w1 = (const float*)d_in[19];
    const float* ffn_b1 = (const float*)d_in[20];
    const float* ffn_w2 = (const float*)d_in[21];
    const float* ffn_b2 = (const float*)d_in[22];
    const float* ln2_g  = (const float*)d_in[23];
    const float* ln2_b  = (const float*)d_in[24];
    const float* ln_g   = (const float*)d_in[25];
    const float* ln_b   = (const float*)d_in[26];
    const float* lin_w  = (const float*)d_in[27];
    const float* lin_b  = (const float*)d_in[28];
    const float* dec_w1 = (const float*)d_in[29];
    const float* dec_b1 = (const float*)d_in[30];
    const float* dec_w2 = (const float*)d_in[31];
    const float* dec_b2 = (const float*)d_in[32];

    float* ws    = (float*)d_ws;
    float* f_x   = ws;
    float* f_q   = ws + 4194304;
    float* f_k   = ws + 8388608;
    float* f_v   = ws + 12582912;
    float* f_t   = ws + 16777216;
    float* f_mid = ws + 4194304;    // aliases q/k/v/t (dead during FFN)
    float* f_t2  = ws + 20971520;

    float* outp  = (float*)d_out;
    float* o_dec = outp;                      // (16,64,1)   = 1024
    float* o_h1  = outp + 1024;               // (16,64,512) = 524288
    float* o_h2  = outp + 1024 + 524288;      // (16,64,512) = 524288

    dim3 g512(4, 64), g2048(16, 64), gsm(4, 8);

    // feature encoder + shared LN
    fe1_kernel<<<16384, 256, 0, stream>>>(feat, fe_w1, fe_b1, f_t);
    gemm_kernel<0><<<g512, 256, 0, stream>>>(f_t, fe_w2, fe_b2, nullptr, f_x, 512, 512);
    ln_kernel<<<2048, 256, 0, stream>>>(f_x, f_x, ln_g, ln_b);

    for (int l = 0; l < 4; l++) {
        gemm_kernel<0><<<g512, 256, 0, stream>>>(f_x, wq + (size_t)l * 262144, bq + l * 512, nullptr, f_q, 512, 512);
        gemm_kernel<0><<<g512, 256, 0, stream>>>(f_x, wk + (size_t)l * 262144, bk + l * 512, nullptr, f_k, 512, 512);
        gemm_kernel<0><<<g512, 256, 0, stream>>>(f_x, wv + (size_t)l * 262144, bv + l * 512, nullptr, f_v, 512, 512);
        attn_kernel<<<dim3(16, 16), 256, 0, stream>>>(f_q, f_k, f_v, rpos,
                                                      wp + (size_t)l * 1536, bp + (size_t)l * 512, f_t);
        gemm_kernel<0><<<g512, 256, 0, stream>>>(f_t, wo + (size_t)l * 262144, bo + l * 512, f_x, f_q, 512, 512);
        ln_kernel<<<2048, 256, 0, stream>>>(f_q, f_x, ln1_g + l * 512, ln1_b + l * 512);
        gemm_kernel<1><<<g2048, 256, 0, stream>>>(f_x, ffn_w1 + (size_t)l * 1048576, ffn_b1 + l * 2048, nullptr, f_mid, 512, 2048);
        gemm_kernel<0><<<g512, 256, 0, stream>>>(f_mid, ffn_w2 + (size_t)l * 1048576, ffn_b2 + l * 512, f_x, f_t2, 2048, 512);
        ln_kernel<<<2048, 256, 0, stream>>>(f_t2, f_x, ln2_g + l * 512, ln2_b + l * 512);
    }

    // masked gather + heads
    gather_kernel<<<512, 256, 0, stream>>>(f_x, mpos, o_h1);
    gemm_kernel<2><<<gsm, 256, 0, stream>>>(o_h1, lin_w, lin_b, nullptr, f_t, 512, 512);
    ln_kernel<<<256, 256, 0, stream>>>(f_t, o_h2, ln_g, ln_b);
    gemm_kernel<0><<<gsm, 256, 0, stream>>>(o_h2, dec_w1, dec_b1, nullptr, f_q, 512, 512);
    dec2_kernel<<<256, 256, 0, stream>>>(f_q, dec_w2, dec_b2, o_dec);
}

// Round 3
// 1622.456 us; speedup vs baseline: 3.1686x; 3.1686x over previous
//
#include <hip/hip_runtime.h>
#include <hip/hip_bf16.h>
#include <math.h>

// SpaFormer forward. bf16-MFMA GEMMs + per-head online-softmax attention.
// B=16 N=512 L=4 H=8 DK=DV=64 DM=512 DI=2048 M=64
//
// ws layout (bytes), total ~81.8 MB (< 100.7 MB proven in round 2):
//   f_x   f32  @ 0          16,777,216   (post-LN x, residual stream)
//   pre   f32  @ 16,777,216 16,777,216   (pre-LN GEMM outputs)
//   qkvb  bf16 @ 33,554,432 25,165,824   ([8192][1536] fused q|k|v)
//   tb    bf16 @ 58,720,256  8,388,608   (fe1 out / attn out; h1b/h2b later)
//   midb  bf16 @ 33,554,432 33,554,432   (FFN mid; aliases qkvb+tb, dead then)
//   xb    bf16 @ 67,108,864  8,388,608   (bf16 copy of x)
//   wT    bf16 @ 75,497,472  6,291,456   (per-layer transposed weights)
//   qkbias f32 @ 81,788,928     24,576   (packed bq|bk|bv, 4 layers)

using bf16   = __bf16;
using bf16x4 = __attribute__((ext_vector_type(4))) __bf16;
using bf16x8 = __attribute__((ext_vector_type(8))) __bf16;
using f32x4  = __attribute__((ext_vector_type(4))) float;

__device__ __forceinline__ void mfma16(f32x4& d, bf16x8 a, bf16x8 b) {
    // D = A(16x32) * B(32x16) + D ; C/D layout: col=lane&15, row=(lane>>4)*4+reg
    asm("v_mfma_f32_16x16x32_bf16 %0, %1, %2, %0" : "+v"(d) : "v"(a), "v"(b));
}

// ---------------- pack bq|bk|bv into [L][1536] ----------------
__global__ __launch_bounds__(256) void packb_kernel(
        const float* __restrict__ bq, const float* __restrict__ bk,
        const float* __restrict__ bv, float* __restrict__ out) {
    int i = blockIdx.x * 256 + threadIdx.x;
    if (i >= 6144) return;
    int l = i / 1536, c = i % 1536;
    float v = c < 512 ? bq[l * 512 + c] : c < 1024 ? bk[l * 512 + c - 512]
                                                   : bv[l * 512 + c - 1024];
    out[i] = v;
}

// ---------------- transpose fp32 [K][N] -> bf16 [N][K] ----------------
__global__ __launch_bounds__(256) void transpose_kernel(
        const float* __restrict__ src, bf16* __restrict__ dst, int K, int N) {
    __shared__ float t[32][33];
    int n0 = blockIdx.x * 32, k0 = blockIdx.y * 32;
    int tx = threadIdx.x & 31, ty = threadIdx.x >> 5;   // 32 x 8
#pragma unroll
    for (int i = 0; i < 4; i++)
        t[ty + i * 8][tx] = src[(size_t)(k0 + ty + i * 8) * N + n0 + tx];
    __syncthreads();
#pragma unroll
    for (int i = 0; i < 4; i++)
        dst[(size_t)(n0 + ty + i * 8) * K + k0 + tx] = (bf16)t[tx][ty + i * 8];
}

// ---------------- feature-encoder first linear (K=3), bf16 out ----------------
__global__ __launch_bounds__(256) void fe1_kernel(
        const float* __restrict__ feat, const float* __restrict__ w1,
        const float* __restrict__ b1, bf16* __restrict__ out) {
    int idx = blockIdx.x * 256 + threadIdx.x;   // 8192*512
    int r = idx >> 9, j = idx & 511;
    float f0 = feat[r * 3 + 0], f1 = feat[r * 3 + 1], f2 = feat[r * 3 + 2];
    out[(size_t)r * 512 + j] = (bf16)
        fmaf(f0, w1[j], fmaf(f1, w1[512 + j], fmaf(f2, w1[1024 + j], b1[j])));
}

// ---------------- bf16 MFMA GEMM: C = A[M][K] @ Bt[N][K]^T + bias (+res) ----------------
// 128x128 tile, BK=64, 4 waves (64x64 each), double-buffered LDS, XOR-swizzled
// (pre-swizzled global source + swizzled ds_read: rule both-sides-or-neither).
// EPI: 0 none, 1 relu, 2 gelu(erf). WF32/WB16: fp32 / bf16 output writes.
template<int EPI, bool WF32, bool WB16>
__global__ __launch_bounds__(256) void mm_kernel(
        const bf16* __restrict__ A, const bf16* __restrict__ Bt,
        const float* __restrict__ bias, const float* __restrict__ res,
        float* __restrict__ Cf, bf16* __restrict__ Cb,
        int M, int N, int K) {
    __shared__ bf16 Al[2][8192];
    __shared__ bf16 Bl[2][8192];
    const int tid = threadIdx.x;
    const int lane = tid & 63, wid = tid >> 6;
    const int r0 = blockIdx.y * 128, c0 = blockIdx.x * 128;
    const int wr = (wid >> 1) * 64, wc = (wid & 1) * 64;

    f32x4 acc[4][4] = {};

    const int kTiles = K >> 6;

#define STAGE(buf, kt)                                                                   \
    {                                                                                    \
        const bf16* ga = A + (size_t)r0 * K + (kt) * 64;                                 \
        const bf16* gb = Bt + (size_t)c0 * K + (kt) * 64;                                \
        _Pragma("unroll")                                                                \
        for (int i_ = 0; i_ < 4; i_++) {                                                 \
            int s = tid + i_ * 256;                                                      \
            int row = s >> 3;                                                            \
            int ssl = (s & 7) ^ (row & 7);                                               \
            __builtin_amdgcn_global_load_lds(                                            \
                (const __attribute__((address_space(1))) void*)(ga + (size_t)row * K + ssl * 8), \
                (__attribute__((address_space(3))) void*)(&Al[buf][s * 8]), 16, 0, 0);   \
            __builtin_amdgcn_global_load_lds(                                            \
                (const __attribute__((address_space(1))) void*)(gb + (size_t)row * K + ssl * 8), \
                (__attribute__((address_space(3))) void*)(&Bl[buf][s * 8]), 16, 0, 0);   \
        }                                                                                \
    }

    STAGE(0, 0);
    __syncthreads();

    for (int kt = 0; kt < kTiles; kt++) {
        if (kt + 1 < kTiles) STAGE((kt + 1) & 1, kt + 1);
        const bf16* al = Al[kt & 1];
        const bf16* bl = Bl[kt & 1];
#pragma unroll
        for (int kk = 0; kk < 2; kk++) {
            bf16x8 af[4], bfr[4];
#pragma unroll
            for (int i = 0; i < 4; i++) {
                int arow = wr + i * 16 + (lane & 15);
                int slot = kk * 4 + (lane >> 4);
                af[i] = *(const bf16x8*)(al + arow * 64 + ((slot ^ (arow & 7)) << 3));
                int brow = wc + i * 16 + (lane & 15);
                bfr[i] = *(const bf16x8*)(bl + brow * 64 + ((slot ^ (brow & 7)) << 3));
            }
#pragma unroll
            for (int i = 0; i < 4; i++)
#pragma unroll
                for (int j = 0; j < 4; j++)
                    mfma16(acc[i][j], af[i], bfr[j]);
        }
        __syncthreads();
    }
#undef STAGE

    asm volatile("s_nop 7\n\ts_nop 7");   // MFMA->VALU read hazard guard (asm path)

#pragma unroll
    for (int i = 0; i < 4; i++)
#pragma unroll
        for (int j = 0; j < 4; j++)
#pragma unroll
            for (int q = 0; q < 4; q++) {
                int row = r0 + wr + i * 16 + ((lane >> 4) << 2) + q;
                int col = c0 + wc + j * 16 + (lane & 15);
                float v = acc[i][j][q] + bias[col];
                if (res) v += res[(size_t)row * N + col];
                if (EPI == 1) v = fmaxf(v, 0.f);
                if (EPI == 2) v = 0.5f * v * (1.f + erff(v * 0.7071067811865475f));
                if (WF32) Cf[(size_t)row * N + col] = v;
                if (WB16) Cb[(size_t)row * N + col] = (bf16)v;
            }
}

// ---------------- LayerNorm over 512, one wave per row, f32+bf16 out ----------------
__global__ __launch_bounds__(256) void ln_kernel(
        const float* __restrict__ in, float* __restrict__ outf, bf16* __restrict__ outb,
        const float* __restrict__ g, const float* __restrict__ b) {
    const int lane = threadIdx.x & 63;
    const size_t row = (size_t)blockIdx.x * 4 + (threadIdx.x >> 6);
    const float* x = in + row * 512;
    float4 a0 = *(const float4*)&x[lane * 4];
    float4 a1 = *(const float4*)&x[256 + lane * 4];
    float s = a0.x + a0.y + a0.z + a0.w + a1.x + a1.y + a1.z + a1.w;
#pragma unroll
    for (int off = 32; off >= 1; off >>= 1) s += __shfl_xor(s, off);
    float mean = s * (1.f / 512.f);
    float d, vs = 0.f;
    d = a0.x - mean; vs += d * d;  d = a0.y - mean; vs += d * d;
    d = a0.z - mean; vs += d * d;  d = a0.w - mean; vs += d * d;
    d = a1.x - mean; vs += d * d;  d = a1.y - mean; vs += d * d;
    d = a1.z - mean; vs += d * d;  d = a1.w - mean; vs += d * d;
#pragma unroll
    for (int off = 32; off >= 1; off >>= 1) vs += __shfl_xor(vs, off);
    float inv = rsqrtf(vs * (1.f / 512.f) + 1e-6f);
    float4 g0 = *(const float4*)&g[lane * 4];
    float4 g1 = *(const float4*)&g[256 + lane * 4];
    float4 b0 = *(const float4*)&b[lane * 4];
    float4 b1v = *(const float4*)&b[256 + lane * 4];
    float o[8];
    o[0] = (a0.x - mean) * inv * g0.x + b0.x;
    o[1] = (a0.y - mean) * inv * g0.y + b0.y;
    o[2] = (a0.z - mean) * inv * g0.z + b0.z;
    o[3] = (a0.w - mean) * inv * g0.w + b0.w;
    o[4] = (a1.x - mean) * inv * g1.x + b1v.x;
    o[5] = (a1.y - mean) * inv * g1.y + b1v.y;
    o[6] = (a1.z - mean) * inv * g1.z + b1v.z;
    o[7] = (a1.w - mean) * inv * g1.w + b1v.w;
    float* y = outf + row * 512;
    *(float4*)&y[lane * 4] = make_float4(o[0], o[1], o[2], o[3]);
    *(float4*)&y[256 + lane * 4] = make_float4(o[4], o[5], o[6], o[7]);
    bf16x4 p0, p1;
#pragma unroll
    for (int i = 0; i < 4; i++) { p0[i] = (bf16)o[i]; p1[i] = (bf16)o[4 + i]; }
    *(bf16x4*)&outb[row * 512 + lane * 4] = p0;
    *(bf16x4*)&outb[row * 512 + 256 + lane * 4] = p1;
}

// ---------------- fused attention, per-(b,h,qtile) blocks, online softmax ----------------
// grid (16, 128): blockIdx.y -> b = y>>3, h = y&7. 32 q-rows/block, kv chunks of 128.
// q/k/v are bf16 slices of the fused [8192][1536] buffer (stride 1536). fp32 math.
__global__ __launch_bounds__(256, 2) void attn_kernel(
        const bf16* __restrict__ qb, const bf16* __restrict__ kb, const bf16* __restrict__ vb,
        const float* __restrict__ rpos, const float* __restrict__ wp,
        const float* __restrict__ bp, bf16* __restrict__ out) {
    __shared__ float qs[32][68];
    __shared__ float kv[128][68];
    __shared__ float sc[32][132];
    __shared__ float qw3[32][4];
    const int tid = threadIdx.x;
    const int b = blockIdx.y >> 3, h = blockIdx.y & 7;
    const int n0 = blockIdx.x * 32;
    const float scale = 0.125f;

    // load q tile (bf16 -> f32 LDS)
    {
        int r = tid >> 3, c = (tid & 7) * 8;
        bf16x8 v8 = *(const bf16x8*)&qb[((size_t)(b * 512 + n0 + r)) * 1536 + h * 64 + c];
#pragma unroll
        for (int i = 0; i < 8; i++) qs[r][c + i] = (float)v8[i];
    }
    __syncthreads();
    if (tid < 128) {     // qw3[r] = {q.wp0, q.wp1, q.wp2, q.bp}
        int r = tid >> 2, j = tid & 3;
        const float* wvec = (j < 3) ? (wp + ((size_t)j * 8 + h) * 64) : (bp + (size_t)h * 64);
        float s = 0.f;
#pragma unroll
        for (int d = 0; d < 64; d++) s = fmaf(qs[r][d], wvec[d], s);
        qw3[r][j] = s;
    }

    float po[8];
#pragma unroll
    for (int j = 0; j < 8; j++) po[j] = 0.f;
    float mrun = -1e30f, lrun = 0.f;

    const int rb = (tid >> 3) & 7;                 // score rows: rb + 8i (strided: bank-clean)
    const int mb = (tid & 7) + (tid >> 6) * 8;     // score cols: mb + 32j (strided: bank-clean)
    const int pr = tid >> 3, pc = tid & 7;         // softmax/PV mapping

    for (int mc = 0; mc < 4; mc++) {
        __syncthreads();
        // stage k chunk (bf16 -> f32)
#pragma unroll
        for (int t = 0; t < 4; t++) {
            int idx = tid + t * 256;
            int mm = idx >> 3, c = (idx & 7) * 8;
            bf16x8 v8 = *(const bf16x8*)&kb[((size_t)(b * 512 + mc * 128 + mm)) * 1536 + h * 64 + c];
#pragma unroll
            for (int i = 0; i < 8; i++) kv[mm][c + i] = (float)v8[i];
        }
        __syncthreads();
        // scores 4x4 per thread
        float a4[4][4];
#pragma unroll
        for (int i = 0; i < 4; i++)
#pragma unroll
            for (int j = 0; j < 4; j++) a4[i][j] = 0.f;
#pragma unroll
        for (int dd = 0; dd < 16; dd++) {
            float4 qv[4], kf[4];
#pragma unroll
            for (int i = 0; i < 4; i++) qv[i] = *(float4*)&qs[rb + 8 * i][dd * 4];
#pragma unroll
            for (int j = 0; j < 4; j++) kf[j] = *(float4*)&kv[mb + 32 * j][dd * 4];
#pragma unroll
            for (int i = 0; i < 4; i++)
#pragma unroll
                for (int j = 0; j < 4; j++) {
                    a4[i][j] = fmaf(qv[i].x, kf[j].x, a4[i][j]);
                    a4[i][j] = fmaf(qv[i].y, kf[j].y, a4[i][j]);
                    a4[i][j] = fmaf(qv[i].z, kf[j].z, a4[i][j]);
                    a4[i][j] = fmaf(qv[i].w, kf[j].w, a4[i][j]);
                }
        }
        // rel-pos + store raw scores (chunk-local cols)
#pragma unroll
        for (int i = 0; i < 4; i++) {
            int r = rb + 8 * i;
            float w0 = qw3[r][0], w1 = qw3[r][1], w2 = qw3[r][2], w3 = qw3[r][3];
#pragma unroll
            for (int j = 0; j < 4; j++) {
                int m = mb + 32 * j;
                const float* rp = rpos + (((size_t)(b * 512) + n0 + r) * 512 + mc * 128 + m) * 3;
                float rel = fmaf(w0, rp[0], fmaf(w1, rp[1], fmaf(w2, rp[2], w3)));
                sc[r][m] = a4[i][j] + rel;
            }
        }
        __syncthreads();
        // online softmax over this chunk (8 lanes per row)
        {
            float mx = -1e30f;
#pragma unroll
            for (int t = 0; t < 16; t++) mx = fmaxf(mx, sc[pr][pc + 8 * t]);
            mx = fmaxf(mx, __shfl_xor(mx, 1));
            mx = fmaxf(mx, __shfl_xor(mx, 2));
            mx = fmaxf(mx, __shfl_xor(mx, 4));
            float mnew = fmaxf(mrun, mx);
            float fac = __expf((mrun - mnew) * scale);
            float ls = 0.f;
#pragma unroll
            for (int t = 0; t < 16; t++) {
                int m = pc + 8 * t;
                float e = __expf((sc[pr][m] - mnew) * scale);
                sc[pr][m] = e;
                ls += e;
            }
            ls += __shfl_xor(ls, 1);
            ls += __shfl_xor(ls, 2);
            ls += __shfl_xor(ls, 4);
            lrun = lrun * fac + ls;
#pragma unroll
            for (int j = 0; j < 8; j++) po[j] *= fac;
            mrun = mnew;
        }
        __syncthreads();
        // stage v chunk
#pragma unroll
        for (int t = 0; t < 4; t++) {
            int idx = tid + t * 256;
            int mm = idx >> 3, c = (idx & 7) * 8;
            bf16x8 v8 = *(const bf16x8*)&vb[((size_t)(b * 512 + mc * 128 + mm)) * 1536 + h * 64 + c];
#pragma unroll
            for (int i = 0; i < 8; i++) kv[mm][c + i] = (float)v8[i];
        }
        __syncthreads();
        // PV accumulate
#pragma unroll 8
        for (int mm = 0; mm < 128; mm++) {
            float p = sc[pr][mm];
            float4 va = *(float4*)&kv[mm][pc * 8];
            float4 vvb = *(float4*)&kv[mm][pc * 8 + 4];
            po[0] = fmaf(p, va.x, po[0]);   po[1] = fmaf(p, va.y, po[1]);
            po[2] = fmaf(p, va.z, po[2]);   po[3] = fmaf(p, va.w, po[3]);
            po[4] = fmaf(p, vvb.x, po[4]);  po[5] = fmaf(p, vvb.y, po[5]);
            po[6] = fmaf(p, vvb.z, po[6]);  po[7] = fmaf(p, vvb.w, po[7]);
        }
    }
    float inv = 1.f / lrun;
    bf16x8 o8;
#pragma unroll
    for (int j = 0; j < 8; j++) o8[j] = (bf16)(po[j] * inv);
    *(bf16x8*)&out[((size_t)(b * 512 + n0 + pr)) * 512 + h * 64 + pc * 8] = o8;
}

// ---------------- gather masked positions (f32 out + bf16 copy) ----------------
__global__ __launch_bounds__(256) void gather_kernel(
        const float* __restrict__ x, const int* __restrict__ mp,
        float* __restrict__ h1, bf16* __restrict__ h1b) {
    int idx = blockIdx.x * 256 + threadIdx.x;   // 1024 rows * 128 float4
    int row = idx >> 7, c4 = (idx & 127) * 4;
    int b = row >> 6;
    int src = mp[row];
    float4 v = *(const float4*)&x[((size_t)(b * 512 + src)) * 512 + c4];
    *(float4*)&h1[(size_t)row * 512 + c4] = v;
    bf16x4 p;
    p[0] = (bf16)v.x; p[1] = (bf16)v.y; p[2] = (bf16)v.z; p[3] = (bf16)v.w;
    *(bf16x4*)&h1b[(size_t)row * 512 + c4] = p;
}

// ---------------- final decoder dot (512 -> 1) ----------------
__global__ __launch_bounds__(256) void dec2_kernel(
        const float* __restrict__ dmid, const float* __restrict__ w2,
        const float* __restrict__ b2, float* __restrict__ out) {
    const int lane = threadIdx.x & 63;
    const int row = blockIdx.x * 4 + (threadIdx.x >> 6);
    float s = 0.f;
#pragma unroll
    for (int t = 0; t < 8; t++) {
        int c = lane + t * 64;
        s = fmaf(dmid[(size_t)row * 512 + c], w2[c], s);
    }
#pragma unroll
    for (int off = 32; off >= 1; off >>= 1) s += __shfl_xor(s, off);
    if (lane == 0) out[row] = s + b2[0];
}

extern "C" void kernel_launch(void* const* d_in, const int* in_sizes, int n_in,
                              void* d_out, int out_size, void* d_ws, size_t ws_size,
                              hipStream_t stream) {
    const float* feat   = (const float*)d_in[0];
    const float* rpos   = (const float*)d_in[1];
    const int*   mpos   = (const int*)d_in[2];
    const float* fe_w1  = (const float*)d_in[3];
    const float* fe_b1  = (const float*)d_in[4];
    const float* fe_w2  = (const float*)d_in[5];
    const float* fe_b2  = (const float*)d_in[6];
    const float* wq     = (const float*)d_in[7];
    const float* bq     = (const float*)d_in[8];
    const float* wk     = (const float*)d_in[9];
    const float* bk     = (const float*)d_in[10];
    const float* wv     = (const float*)d_in[11];
    const float* bv     = (const float*)d_in[12];
    const float* wp     = (const float*)d_in[13];
    const float* bp     = (const float*)d_in[14];
    const float* wo     = (const float*)d_in[15];
    const float* bo     = (const float*)d_in[16];
    const float* ln1_g  = (const float*)d_in[17];
    const float* ln1_b  = (const float*)d_in[18];
    const float* ffn_w1 = (const float*)d_in[19];
    const float* ffn_b1 = (const float*)d_in[20];
    const float* ffn_w2 = (const float*)d_in[21];
    const float* ffn_b2 = (const float*)d_in[22];
    const float* ln2_g  = (const float*)d_in[23];
    const float* ln2_b  = (const float*)d_in[24];
    const float* ln_g   = (const float*)d_in[25];
    const float* ln_b   = (const float*)d_in[26];
    const float* lin_w  = (const float*)d_in[27];
    const float* lin_b  = (const float*)d_in[28];
    const float* dec_w1 = (const float*)d_in[29];
    const float* dec_b1 = (const float*)d_in[30];
    const float* dec_w2 = (const float*)d_in[31];
    const float* dec_b2 = (const float*)d_in[32];

    char* W = (char*)d_ws;
    float* f_x    = (float*)(W);
    float* pre    = (float*)(W + 16777216);
    bf16*  qkvb   = (bf16*)(W + 33554432);
    bf16*  tb     = (bf16*)(W + 58720256);
    bf16*  midb   = (bf16*)(W + 33554432);   // aliases qkvb+tb (dead during FFN)
    bf16*  xb     = (bf16*)(W + 67108864);
    bf16*  wT     = (bf16*)(W + 75497472);   // 3,145,728 bf16 rotating
    float* qkbias = (float*)(W + 81788928);
    bf16*  h1b    = tb;                       // layers done when used
    bf16*  h2b    = (bf16*)((char*)tb + 1048576);

    bf16* qT  = wT;                 // [1536][512]  (wq^T|wk^T|wv^T)
    bf16* oT  = wT + 786432;        // [512][512]
    bf16* w1T = wT + 1048576;       // [2048][512]
    bf16* w2T = wT + 2097152;       // [512][2048]

    float* outp  = (float*)d_out;
    float* o_dec = outp;                      // (16,64,1)
    float* o_h1  = outp + 1024;               // (16,64,512)
    float* o_h2  = outp + 1024 + 524288;      // (16,64,512)

    dim3 t512(16, 16), g512(4, 64), gQKV(12, 64), gF1(16, 64), gsm(4, 8);

    packb_kernel<<<24, 256, 0, stream>>>(bq, bk, bv, qkbias);

    // feature encoder + shared LN
    transpose_kernel<<<t512, 256, 0, stream>>>(fe_w2, wT, 512, 512);
    fe1_kernel<<<16384, 256, 0, stream>>>(feat, fe_w1, fe_b1, tb);
    mm_kernel<0, true, false><<<g512, 256, 0, stream>>>(tb, wT, fe_b2, nullptr, pre, nullptr, 8192, 512, 512);
    ln_kernel<<<2048, 256, 0, stream>>>(pre, f_x, xb, ln_g, ln_b);

    for (int l = 0; l < 4; l++) {
        transpose_kernel<<<t512, 256, 0, stream>>>(wq + (size_t)l * 262144, qT, 512, 512);
        transpose_kernel<<<t512, 256, 0, stream>>>(wk + (size_t)l * 262144, qT + 262144, 512, 512);
        transpose_kernel<<<t512, 256, 0, stream>>>(wv + (size_t)l * 262144, qT + 524288, 512, 512);
        transpose_kernel<<<t512, 256, 0, stream>>>(wo + (size_t)l * 262144, oT, 512, 512);
        transpose_kernel<<<dim3(64, 16), 256, 0, stream>>>(ffn_w1 + (size_t)l * 1048576, w1T, 512, 2048);
        transpose_kernel<<<dim3(16, 64), 256, 0, stream>>>(ffn_w2 + (size_t)l * 1048576, w2T, 2048, 512);

        mm_kernel<0, false, true><<<gQKV, 256, 0, stream>>>(xb, qT, qkbias + l * 1536, nullptr, nullptr, qkvb, 8192, 1536, 512);
        attn_kernel<<<dim3(16, 128), 256, 0, stream>>>(qkvb, qkvb + 512, qkvb + 1024, rpos,
                                                       wp + (size_t)l * 1536, bp + (size_t)l * 512, tb);
        mm_kernel<0, true, false><<<g512, 256, 0, stream>>>(tb, oT, bo + l * 512, f_x, pre, nullptr, 8192, 512, 512);
        ln_kernel<<<2048, 256, 0, stream>>>(pre, f_x, xb, ln1_g + l * 512, ln1_b + l * 512);
        mm_kernel<1, false, true><<<gF1, 256, 0, stream>>>(xb, w1T, ffn_b1 + l * 2048, nullptr, nullptr, midb, 8192, 2048, 512);
        mm_kernel<0, true, false><<<g512, 256, 0, stream>>>(midb, w2T, ffn_b2 + l * 512, f_x, pre, nullptr, 8192, 512, 2048);
        ln_kernel<<<2048, 256, 0, stream>>>(pre, f_x, xb, ln2_g + l * 512, ln2_b + l * 512);
    }

    // masked gather + heads
    gather_kernel<<<512, 256, 0, stream>>>(f_x, mpos, o_h1, h1b);
    transpose_kernel<<<t512, 256, 0, stream>>>(lin_w, wT, 512, 512);
    transpose_kernel<<<t512, 256, 0, stream>>>(dec_w1, wT + 262144, 512, 512);
    mm_kernel<2, true, false><<<gsm, 256, 0, stream>>>(h1b, wT, lin_b, nullptr, pre, nullptr, 1024, 512, 512);
    ln_kernel<<<256, 256, 0, stream>>>(pre, o_h2, h2b, ln_g, ln_b);
    mm_kernel<0, true, false><<<gsm, 256, 0, stream>>>(h2b, wT + 262144, dec_b1, nullptr, pre, nullptr, 1024, 512, 512);
    dec2_kernel<<<256, 256, 0, stream>>>(pre, dec_w2, dec_b2, o_dec);
}

// Round 5
// 1554.237 us; speedup vs baseline: 3.3076x; 1.0439x over previous
//
#include <hip/hip_runtime.h>
#include <hip/hip_bf16.h>
#include <math.h>

// SpaFormer forward. bf16-MFMA GEMMs + MFMA attention w/ fused rel-pos softmax.
// B=16 N=512 L=4 H=8 DK=DV=64 DM=512 DI=2048 M=64
//
// ws layout (bytes), total 93.9 MB:
//   f_x   f32  @ 0           16,777,216  (x / GEMM+LN stream, in-place LN)
//   qkvb  bf16 @ 16,777,216  25,165,824  ([8192][1536] fused q|k|v)
//   tb    bf16 @ 41,943,040   8,388,608  (fe1 out / attn out; h1b/h2b later)
//   midb  bf16 @ 16,777,216  33,554,432  (FFN mid; aliases qkvb+tb, dead then)
//   xb    bf16 @ 50,331,648   8,388,608  (bf16 copy of x)
//   vT    bf16 @ 58,720,256   8,388,608  ([b*8+h][64][512] transposed V)
//   wTall bf16 @ 67,108,864  26,738,688  (ALL transposed weights, one kernel)
//   qkbias f32 @ 93,847,552      24,576  (packed bq|bk|bv)

using bf16   = __bf16;
using bf16x4 = __attribute__((ext_vector_type(4))) __bf16;
using bf16x8 = __attribute__((ext_vector_type(8))) __bf16;
using f32x4  = __attribute__((ext_vector_type(4))) float;

__device__ __forceinline__ void mfma16(f32x4& d, bf16x8 a, bf16x8 b) {
    // D(16x16) = A(16x32)*B(32x16)+D. A/B: lane holds row/col (lane&15),
    // k = (lane>>4)*8+0..7. D: col=lane&15, row=(lane>>4)*4+reg.
    asm("v_mfma_f32_16x16x32_bf16 %0, %1, %2, %0" : "+v"(d) : "v"(a), "v"(b));
}

// ---------------- pack bq|bk|bv into [L][1536] ----------------
__global__ __launch_bounds__(256) void packb_kernel(
        const float* __restrict__ bq, const float* __restrict__ bk,
        const float* __restrict__ bv, float* __restrict__ out) {
    int i = blockIdx.x * 256 + threadIdx.x;
    if (i >= 6144) return;
    int l = i / 1536, c = i % 1536;
    out[i] = c < 512 ? bq[l * 512 + c] : c < 1024 ? bk[l * 512 + c - 512]
                                                  : bv[l * 512 + c - 1024];
}

// ---------------- ALL weight transposes, fp32 [K][N] -> bf16 [N][K] ----------------
// One kernel, segment ladder. 13056 tile-blocks of 32x32.
__global__ __launch_bounds__(256) void transall_kernel(
        const float* __restrict__ fe_w2, const float* __restrict__ wq,
        const float* __restrict__ wk, const float* __restrict__ wv,
        const float* __restrict__ wo, const float* __restrict__ w1,
        const float* __restrict__ w2, const float* __restrict__ lin_w,
        const float* __restrict__ dec_w1, bf16* __restrict__ dst) {
    __shared__ float t[32][33];
    int id = blockIdx.x;
    const float* src; bf16* d; int K, N, ti;
    if (id < 256)        { src = fe_w2;  d = dst + 12582912; K = 512; N = 512; ti = id; }
    else if (id < 12544) {
        int u = id - 256, l = u / 3072, r = u % 3072;
        bf16* base = dst + (size_t)l * 3145728;
        if      (r < 256)  { src = wq + (size_t)l * 262144;  d = base;           K = 512;  N = 512;  ti = r; }
        else if (r < 512)  { src = wk + (size_t)l * 262144;  d = base + 262144;  K = 512;  N = 512;  ti = r - 256; }
        else if (r < 768)  { src = wv + (size_t)l * 262144;  d = base + 524288;  K = 512;  N = 512;  ti = r - 512; }
        else if (r < 1024) { src = wo + (size_t)l * 262144;  d = base + 786432;  K = 512;  N = 512;  ti = r - 768; }
        else if (r < 2048) { src = w1 + (size_t)l * 1048576; d = base + 1048576; K = 512;  N = 2048; ti = r - 1024; }
        else               { src = w2 + (size_t)l * 1048576; d = base + 2097152; K = 2048; N = 512;  ti = r - 2048; }
    }
    else if (id < 12800) { src = lin_w;  d = dst + 12845056; K = 512; N = 512; ti = id - 12544; }
    else                 { src = dec_w1; d = dst + 13107200; K = 512; N = 512; ti = id - 12800; }
    int nt = N >> 5;
    int n0 = (ti % nt) * 32, k0 = (ti / nt) * 32;
    int tx = threadIdx.x & 31, ty = threadIdx.x >> 5;
#pragma unroll
    for (int i = 0; i < 4; i++)
        t[ty + i * 8][tx] = src[(size_t)(k0 + ty + i * 8) * N + n0 + tx];
    __syncthreads();
#pragma unroll
    for (int i = 0; i < 4; i++)
        d[(size_t)(n0 + ty + i * 8) * K + k0 + tx] = (bf16)t[tx][ty + i * 8];
}

// ---------------- V transpose: qkv v-slice -> vT[b*8+h][64][512] ----------------
__global__ __launch_bounds__(256) void vt_kernel(
        const bf16* __restrict__ qkv, bf16* __restrict__ vT) {
    __shared__ bf16 t[32][33];
    int s = blockIdx.z;                      // b*8+h
    int m0 = blockIdx.x * 32, d0 = blockIdx.y * 32;
    int tx = threadIdx.x & 31, ty = threadIdx.x >> 5;
    int b = s >> 3, h = s & 7;
    const bf16* src = qkv + 1024 + (size_t)h * 64;
#pragma unroll
    for (int i = 0; i < 4; i++)
        t[ty + i * 8][tx] = src[(size_t)(b * 512 + m0 + ty + i * 8) * 1536 + d0 + tx];
    __syncthreads();
#pragma unroll
    for (int i = 0; i < 4; i++)
        vT[((size_t)s * 64 + d0 + ty + i * 8) * 512 + m0 + tx] = t[tx][ty + i * 8];
}

// ---------------- feature-encoder first linear (K=3), bf16 out ----------------
__global__ __launch_bounds__(256) void fe1_kernel(
        const float* __restrict__ feat, const float* __restrict__ w1,
        const float* __restrict__ b1, bf16* __restrict__ out) {
    int idx = blockIdx.x * 256 + threadIdx.x;
    int r = idx >> 9, j = idx & 511;
    float f0 = feat[r * 3 + 0], f1 = feat[r * 3 + 1], f2 = feat[r * 3 + 2];
    out[(size_t)r * 512 + j] = (bf16)
        fmaf(f0, w1[j], fmaf(f1, w1[512 + j], fmaf(f2, w1[1024 + j], b1[j])));
}

// ---------------- bf16 MFMA GEMM (unchanged from round 3, proven) ----------------
template<int EPI, bool WF32, bool WB16>
__global__ __launch_bounds__(256) void mm_kernel(
        const bf16* __restrict__ A, const bf16* __restrict__ Bt,
        const float* __restrict__ bias, const float* __restrict__ res,
        float* __restrict__ Cf, bf16* __restrict__ Cb,
        int M, int N, int K) {
    __shared__ bf16 Al[2][8192];
    __shared__ bf16 Bl[2][8192];
    const int tid = threadIdx.x;
    const int lane = tid & 63, wid = tid >> 6;
    const int r0 = blockIdx.y * 128, c0 = blockIdx.x * 128;
    const int wr = (wid >> 1) * 64, wc = (wid & 1) * 64;

    f32x4 acc[4][4] = {};
    const int kTiles = K >> 6;

#define STAGE(buf, kt)                                                                   \
    {                                                                                    \
        const bf16* ga = A + (size_t)r0 * K + (kt) * 64;                                 \
        const bf16* gb = Bt + (size_t)c0 * K + (kt) * 64;                                \
        _Pragma("unroll")                                                                \
        for (int i_ = 0; i_ < 4; i_++) {                                                 \
            int s = tid + i_ * 256;                                                      \
            int row = s >> 3;                                                            \
            int ssl = (s & 7) ^ (row & 7);                                               \
            __builtin_amdgcn_global_load_lds(                                            \
                (const __attribute__((address_space(1))) void*)(ga + (size_t)row * K + ssl * 8), \
                (__attribute__((address_space(3))) void*)(&Al[buf][s * 8]), 16, 0, 0);   \
            __builtin_amdgcn_global_load_lds(                                            \
                (const __attribute__((address_space(1))) void*)(gb + (size_t)row * K + ssl * 8), \
                (__attribute__((address_space(3))) void*)(&Bl[buf][s * 8]), 16, 0, 0);   \
        }                                                                                \
    }

    STAGE(0, 0);
    __syncthreads();

    for (int kt = 0; kt < kTiles; kt++) {
        if (kt + 1 < kTiles) STAGE((kt + 1) & 1, kt + 1);
        const bf16* al = Al[kt & 1];
        const bf16* bl = Bl[kt & 1];
#pragma unroll
        for (int kk = 0; kk < 2; kk++) {
            bf16x8 af[4], bfr[4];
#pragma unroll
            for (int i = 0; i < 4; i++) {
                int arow = wr + i * 16 + (lane & 15);
                int slot = kk * 4 + (lane >> 4);
                af[i] = *(const bf16x8*)(al + arow * 64 + ((slot ^ (arow & 7)) << 3));
                int brow = wc + i * 16 + (lane & 15);
                bfr[i] = *(const bf16x8*)(bl + brow * 64 + ((slot ^ (brow & 7)) << 3));
            }
#pragma unroll
            for (int i = 0; i < 4; i++)
#pragma unroll
                for (int j = 0; j < 4; j++)
                    mfma16(acc[i][j], af[i], bfr[j]);
        }
        __syncthreads();
    }
#undef STAGE

    asm volatile("s_nop 7\n\ts_nop 7");

#pragma unroll
    for (int i = 0; i < 4; i++)
#pragma unroll
        for (int j = 0; j < 4; j++)
#pragma unroll
            for (int q = 0; q < 4; q++) {
                int row = r0 + wr + i * 16 + ((lane >> 4) << 2) + q;
                int col = c0 + wc + j * 16 + (lane & 15);
                float v = acc[i][j][q] + bias[col];
                if (res) v += res[(size_t)row * N + col];
                if (EPI == 1) v = fmaxf(v, 0.f);
                if (EPI == 2) v = 0.5f * v * (1.f + erff(v * 0.7071067811865475f));
                if (WF32) Cf[(size_t)row * N + col] = v;
                if (WB16) Cb[(size_t)row * N + col] = (bf16)v;
            }
}

// ---------------- LayerNorm over 512 (in-place capable), f32 + bf16 out ----------------
__global__ __launch_bounds__(256) void ln_kernel(
        const float* __restrict__ in, float* __restrict__ outf, bf16* __restrict__ outb,
        const float* __restrict__ g, const float* __restrict__ b) {
    const int lane = threadIdx.x & 63;
    const size_t row = (size_t)blockIdx.x * 4 + (threadIdx.x >> 6);
    const float* x = in + row * 512;
    float4 a0 = *(const float4*)&x[lane * 4];
    float4 a1 = *(const float4*)&x[256 + lane * 4];
    float s = a0.x + a0.y + a0.z + a0.w + a1.x + a1.y + a1.z + a1.w;
#pragma unroll
    for (int off = 32; off >= 1; off >>= 1) s += __shfl_xor(s, off);
    float mean = s * (1.f / 512.f);
    float d, vs = 0.f;
    d = a0.x - mean; vs += d * d;  d = a0.y - mean; vs += d * d;
    d = a0.z - mean; vs += d * d;  d = a0.w - mean; vs += d * d;
    d = a1.x - mean; vs += d * d;  d = a1.y - mean; vs += d * d;
    d = a1.z - mean; vs += d * d;  d = a1.w - mean; vs += d * d;
#pragma unroll
    for (int off = 32; off >= 1; off >>= 1) vs += __shfl_xor(vs, off);
    float inv = rsqrtf(vs * (1.f / 512.f) + 1e-6f);
    float4 g0 = *(const float4*)&g[lane * 4];
    float4 g1 = *(const float4*)&g[256 + lane * 4];
    float4 b0 = *(const float4*)&b[lane * 4];
    float4 b1v = *(const float4*)&b[256 + lane * 4];
    float o[8];
    o[0] = (a0.x - mean) * inv * g0.x + b0.x;
    o[1] = (a0.y - mean) * inv * g0.y + b0.y;
    o[2] = (a0.z - mean) * inv * g0.z + b0.z;
    o[3] = (a0.w - mean) * inv * g0.w + b0.w;
    o[4] = (a1.x - mean) * inv * g1.x + b1v.x;
    o[5] = (a1.y - mean) * inv * g1.y + b1v.y;
    o[6] = (a1.z - mean) * inv * g1.z + b1v.z;
    o[7] = (a1.w - mean) * inv * g1.w + b1v.w;
    float* y = outf + row * 512;
    *(float4*)&y[lane * 4] = make_float4(o[0], o[1], o[2], o[3]);
    *(float4*)&y[256 + lane * 4] = make_float4(o[4], o[5], o[6], o[7]);
    bf16x4 p0, p1;
#pragma unroll
    for (int i = 0; i < 4; i++) { p0[i] = (bf16)o[i]; p1[i] = (bf16)o[4 + i]; }
    *(bf16x4*)&outb[row * 512 + lane * 4] = p0;
    *(bf16x4*)&outb[row * 512 + 256 + lane * 4] = p1;
}

// ---------------- MFMA attention, grid (8 qtiles, 128 bh), 4 waves x 16 rows ----------------
__global__ __launch_bounds__(256, 2) void attn_kernel(
        const bf16* __restrict__ qb, const bf16* __restrict__ kb,
        const bf16* __restrict__ vT, const float* __restrict__ rpos,
        const float* __restrict__ wp, const float* __restrict__ bp,
        bf16* __restrict__ out) {
    __shared__ bf16 p_lds[4][16][128];   // XOR-swizzled P tile per wave
    __shared__ float qw_lds[4][16][4];
    __shared__ bf16 o_lds[4][16][64];
    const int tid = threadIdx.x, lane = tid & 63, wid = tid >> 6;
    const int bh = blockIdx.y, b = bh >> 3, h = bh & 7;
    const int n0 = blockIdx.x * 64 + wid * 16;
    const int lo = lane & 15, hi = lane >> 4;
    const float scale = 0.125f;

    const bf16* qbase = qb + (size_t)(b * 512) * 1536 + h * 64;
    const bf16* kbase = kb + (size_t)(b * 512) * 1536 + h * 64;
    const bf16* vbase = vT + (size_t)bh * 32768;
    const float* rbase = rpos + (size_t)(b * 512 + n0) * 1536;   // rows*512*3

    // qw3 per row: lane -> (r = lane>>2, j = lane&3): q . wp[j] (j<3) / q . bp
    {
        int r = lane >> 2, j = lane & 3;
        const float* wvec = (j < 3) ? wp + ((size_t)j * 8 + h) * 64 : bp + (size_t)h * 64;
        const bf16* qr = qbase + (size_t)(n0 + r) * 1536;
        float s = 0.f;
#pragma unroll
        for (int c8 = 0; c8 < 8; c8++) {
            bf16x8 v8 = *(const bf16x8*)(qr + c8 * 8);
#pragma unroll
            for (int i = 0; i < 8; i++) s = fmaf((float)v8[i], wvec[c8 * 8 + i], s);
        }
        qw_lds[wid][r][j] = s;
    }
    bf16x8 af0 = *(const bf16x8*)(qbase + (size_t)(n0 + lo) * 1536 + hi * 8);
    bf16x8 af1 = *(const bf16x8*)(qbase + (size_t)(n0 + lo) * 1536 + 32 + hi * 8);
    __syncthreads();
    float qw[4][4];
#pragma unroll
    for (int q = 0; q < 4; q++)
#pragma unroll
        for (int j = 0; j < 4; j++) qw[q][j] = qw_lds[wid][hi * 4 + q][j];

    f32x4 oacc[4] = {};
    float mrun[4] = {-1e30f, -1e30f, -1e30f, -1e30f};
    float lrun[4] = {0.f, 0.f, 0.f, 0.f};

    for (int mc = 0; mc < 4; mc++) {
        const int m0 = mc * 128;
        // ---- QK^T: 8 m-tiles of 16, K/B-frags straight from global ----
        f32x4 st[8];
#pragma unroll
        for (int t = 0; t < 8; t++) {
            const bf16* kr = kbase + (size_t)(m0 + t * 16 + lo) * 1536 + hi * 8;
            bf16x8 kf0 = *(const bf16x8*)kr;
            bf16x8 kf1 = *(const bf16x8*)(kr + 32);
            f32x4 z = {};
            mfma16(z, af0, kf0);
            mfma16(z, af1, kf1);
            st[t] = z;
        }
        asm volatile("s_nop 7\n\ts_nop 7");   // MFMA->VALU hazard
        // ---- rel-pos: st += qw . rpos ----
#pragma unroll
        for (int t = 0; t < 8; t++) {
#pragma unroll
            for (int q = 0; q < 4; q++) {
                const float* rp = rbase + ((size_t)(hi * 4 + q) * 512 + m0 + t * 16 + lo) * 3;
                st[t][q] += fmaf(qw[q][0], rp[0],
                             fmaf(qw[q][1], rp[1], fmaf(qw[q][2], rp[2], qw[q][3])));
            }
        }
        // ---- online softmax (rows = hi*4+q, cross-lane over lo nibble) ----
        float fac[4];
#pragma unroll
        for (int q = 0; q < 4; q++) {
            float mx = st[0][q];
#pragma unroll
            for (int t = 1; t < 8; t++) mx = fmaxf(mx, st[t][q]);
            mx = fmaxf(mx, __shfl_xor(mx, 1));
            mx = fmaxf(mx, __shfl_xor(mx, 2));
            mx = fmaxf(mx, __shfl_xor(mx, 4));
            mx = fmaxf(mx, __shfl_xor(mx, 8));
            float mnew = fmaxf(mrun[q], mx);
            fac[q] = __expf((mrun[q] - mnew) * scale);
            float ls = 0.f;
#pragma unroll
            for (int t = 0; t < 8; t++) {
                float e = __expf((st[t][q] - mnew) * scale);
                st[t][q] = e;
                ls += e;
            }
            ls += __shfl_xor(ls, 1);
            ls += __shfl_xor(ls, 2);
            ls += __shfl_xor(ls, 4);
            ls += __shfl_xor(ls, 8);
            lrun[q] = lrun[q] * fac[q] + ls;
            mrun[q] = mnew;
        }
#pragma unroll
        for (int dt = 0; dt < 4; dt++) {
            oacc[dt][0] *= fac[0]; oacc[dt][1] *= fac[1];
            oacc[dt][2] *= fac[2]; oacc[dt][3] *= fac[3];
        }
        // ---- P -> LDS (bf16), 8-elem-chunk XOR swizzle, D-layout -> A-layout ----
#pragma unroll
        for (int t = 0; t < 8; t++) {
#pragma unroll
            for (int q = 0; q < 4; q++) {
                int rl = hi * 4 + q;
                int c = t * 16 + lo;
                int cs = (((c >> 3) ^ (rl & 7)) << 3) | (c & 7);
                p_lds[wid][rl][cs] = (bf16)st[t][q];
            }
        }
        // ---- PV: A = P from LDS, B = vT rows (contiguous) ----
#pragma unroll
        for (int ks = 0; ks < 4; ks++) {
            int chunk = (ks * 4 + hi) ^ (lo & 7);
            bf16x8 pa = *(const bf16x8*)&p_lds[wid][lo][chunk << 3];
#pragma unroll
            for (int dt = 0; dt < 4; dt++) {
                bf16x8 vf = *(const bf16x8*)(vbase + (size_t)(dt * 16 + lo) * 512 + m0 + ks * 32 + hi * 8);
                mfma16(oacc[dt], pa, vf);
            }
        }
    }
    asm volatile("s_nop 7\n\ts_nop 7");
    // ---- epilogue: normalize, bounce through LDS, coalesced bf16 write ----
    float inv[4];
#pragma unroll
    for (int q = 0; q < 4; q++) inv[q] = 1.f / lrun[q];
#pragma unroll
    for (int dt = 0; dt < 4; dt++)
#pragma unroll
        for (int q = 0; q < 4; q++)
            o_lds[wid][hi * 4 + q][dt * 16 + lo] = (bf16)(oacc[dt][q] * inv[q]);
    {
        int r = lane >> 2, c = (lane & 3) * 16;
        bf16x8 w0 = *(const bf16x8*)&o_lds[wid][r][c];
        bf16x8 w1 = *(const bf16x8*)&o_lds[wid][r][c + 8];
        bf16* op = out + (size_t)(b * 512 + n0 + r) * 512 + h * 64 + c;
        *(bf16x8*)op = w0;
        *(bf16x8*)(op + 8) = w1;
    }
}

// ---------------- gather masked positions (f32 out + bf16 copy) ----------------
__global__ __launch_bounds__(256) void gather_kernel(
        const float* __restrict__ x, const int* __restrict__ mp,
        float* __restrict__ h1, bf16* __restrict__ h1b) {
    int idx = blockIdx.x * 256 + threadIdx.x;
    int row = idx >> 7, c4 = (idx & 127) * 4;
    int b = row >> 6;
    int src = mp[row];
    float4 v = *(const float4*)&x[((size_t)(b * 512 + src)) * 512 + c4];
    *(float4*)&h1[(size_t)row * 512 + c4] = v;
    bf16x4 p;
    p[0] = (bf16)v.x; p[1] = (bf16)v.y; p[2] = (bf16)v.z; p[3] = (bf16)v.w;
    *(bf16x4*)&h1b[(size_t)row * 512 + c4] = p;
}

// ---------------- final decoder dot (512 -> 1) ----------------
__global__ __launch_bounds__(256) void dec2_kernel(
        const float* __restrict__ dmid, const float* __restrict__ w2,
        const float* __restrict__ b2, float* __restrict__ out) {
    const int lane = threadIdx.x & 63;
    const int row = blockIdx.x * 4 + (threadIdx.x >> 6);
    float s = 0.f;
#pragma unroll
    for (int t = 0; t < 8; t++) {
        int c = lane + t * 64;
        s = fmaf(dmid[(size_t)row * 512 + c], w2[c], s);
    }
#pragma unroll
    for (int off = 32; off >= 1; off >>= 1) s += __shfl_xor(s, off);
    if (lane == 0) out[row] = s + b2[0];
}

extern "C" void kernel_launch(void* const* d_in, const int* in_sizes, int n_in,
                              void* d_out, int out_size, void* d_ws, size_t ws_size,
                              hipStream_t stream) {
    const float* feat   = (const float*)d_in[0];
    const float* rpos   = (const float*)d_in[1];
    const int*   mpos   = (const int*)d_in[2];
    const float* fe_w1  = (const float*)d_in[3];
    const float* fe_b1  = (const float*)d_in[4];
    const float* fe_w2  = (const float*)d_in[5];
    const float* fe_b2  = (const float*)d_in[6];
    const float* wq     = (const float*)d_in[7];
    const float* bq     = (const float*)d_in[8];
    const float* wk     = (const float*)d_in[9];
    const float* bk     = (const float*)d_in[10];
    const float* wv     = (const float*)d_in[11];
    const float* bv     = (const float*)d_in[12];
    const float* wp     = (const float*)d_in[13];
    const float* bp     = (const float*)d_in[14];
    const float* wo     = (const float*)d_in[15];
    const float* bo     = (const float*)d_in[16];
    const float* ln1_g  = (const float*)d_in[17];
    const float* ln1_b  = (const float*)d_in[18];
    const float* ffn_w1 = (const float*)d_in[19];
    const float* ffn_b1 = (const float*)d_in[20];
    const float* ffn_w2 = (const float*)d_in[21];
    const float* ffn_b2 = (const float*)d_in[22];
    const float* ln2_g  = (const float*)d_in[23];
    const float* ln2_b  = (const float*)d_in[24];
    const float* ln_g   = (const float*)d_in[25];
    const float* ln_b   = (const float*)d_in[26];
    const float* lin_w  = (const float*)d_in[27];
    const float* lin_b  = (const float*)d_in[28];
    const float* dec_w1 = (const float*)d_in[29];
    const float* dec_b1 = (const float*)d_in[30];
    const float* dec_w2 = (const float*)d_in[31];
    const float* dec_b2 = (const float*)d_in[32];

    char* W = (char*)d_ws;
    float* f_x    = (float*)(W);
    bf16*  qkvb   = (bf16*)(W + 16777216);
    bf16*  tb     = (bf16*)(W + 41943040);
    bf16*  midb   = (bf16*)(W + 16777216);   // aliases qkvb+tb (dead during FFN)
    bf16*  xb     = (bf16*)(W + 50331648);
    bf16*  vTb    = (bf16*)(W + 58720256);
    bf16*  wTall  = (bf16*)(W + 67108864);
    float* qkbias = (float*)(W + 93847552);
    bf16*  h1b    = tb;
    bf16*  h2b    = tb + 524288;

    bf16* feT  = wTall + 12582912;
    bf16* linT = wTall + 12845056;
    bf16* decT = wTall + 13107200;

    float* outp  = (float*)d_out;
    float* o_dec = outp;                      // (16,64,1)
    float* o_h1  = outp + 1024;               // (16,64,512)
    float* o_h2  = outp + 1024 + 524288;      // (16,64,512)

    dim3 g512(4, 64), gQKV(12, 64), gF1(16, 64), gsm(4, 8);

    packb_kernel<<<24, 256, 0, stream>>>(bq, bk, bv, qkbias);
    transall_kernel<<<13056, 256, 0, stream>>>(fe_w2, wq, wk, wv, wo, ffn_w1, ffn_w2,
                                               lin_w, dec_w1, wTall);

    // feature encoder + shared LN
    fe1_kernel<<<16384, 256, 0, stream>>>(feat, fe_w1, fe_b1, tb);
    mm_kernel<0, true, false><<<g512, 256, 0, stream>>>(tb, feT, fe_b2, nullptr, f_x, nullptr, 8192, 512, 512);
    ln_kernel<<<2048, 256, 0, stream>>>(f_x, f_x, xb, ln_g, ln_b);

    for (int l = 0; l < 4; l++) {
        bf16* qT  = wTall + (size_t)l * 3145728;
        bf16* oT  = qT + 786432;
        bf16* w1T = qT + 1048576;
        bf16* w2T = qT + 2097152;

        mm_kernel<0, false, true><<<gQKV, 256, 0, stream>>>(xb, qT, qkbias + l * 1536, nullptr, nullptr, qkvb, 8192, 1536, 512);
        vt_kernel<<<dim3(16, 2, 128), 256, 0, stream>>>(qkvb, vTb);
        attn_kernel<<<dim3(8, 128), 256, 0, stream>>>(qkvb, qkvb + 512, vTb, rpos,
                                                      wp + (size_t)l * 1536, bp + (size_t)l * 512, tb);
        mm_kernel<0, true, false><<<g512, 256, 0, stream>>>(tb, oT, bo + l * 512, f_x, f_x, nullptr, 8192, 512, 512);
        ln_kernel<<<2048, 256, 0, stream>>>(f_x, f_x, xb, ln1_g + l * 512, ln1_b + l * 512);
        mm_kernel<1, false, true><<<gF1, 256, 0, stream>>>(xb, w1T, ffn_b1 + l * 2048, nullptr, nullptr, midb, 8192, 2048, 512);
        mm_kernel<0, true, false><<<g512, 256, 0, stream>>>(midb, w2T, ffn_b2 + l * 512, f_x, f_x, nullptr, 8192, 512, 2048);
        ln_kernel<<<2048, 256, 0, stream>>>(f_x, f_x, xb, ln2_g + l * 512, ln2_b + l * 512);
    }

    // masked gather + heads
    gather_kernel<<<512, 256, 0, stream>>>(f_x, mpos, o_h1, h1b);
    mm_kernel<2, true, false><<<gsm, 256, 0, stream>>>(h1b, linT, lin_b, nullptr, f_x, nullptr, 1024, 512, 512);
    ln_kernel<<<256, 256, 0, stream>>>(f_x, o_h2, h2b, ln_g, ln_b);
    mm_kernel<0, true, false><<<gsm, 256, 0, stream>>>(h2b, decT, dec_b1, nullptr, f_x, nullptr, 1024, 512, 512);
    dec2_kernel<<<256, 256, 0, stream>>>(f_x, dec_w2, dec_b2, o_dec);
}